// Round 5
// baseline (63.680 us; speedup 1.0000x reference)
//
#include <hip/hip_runtime.h>

// Analytic collapse of the "quantum conv" model:
//   After RY encoding + CNOT chain, qubit w's bit is the XOR of independent
//   Bernoulli(sin^2(x_j/2)) bits j<=w  ->  <Z_w> = prod_{j<=w} cos(x_j).
//   RZ(patch_params) are diagonal phases; |amp|^2 removes them entirely.
//   out[b] = sigmoid(cos( sum_p sum_w feats[b,4p+w] * W[4p+w] ))
//   per-patch Horner: c0*(W0 + c1*(W1 + c2*(W2 + c3*W3))).
// Patch p=(gi,gj), 14x14 grid of 2x2 patches, pixels row-major:
//   offsets base, base+1, base+28, base+29, base = 56*gi + 2*gj.
//
// Dtypes (established over R0-R4): x f32, cp f32, OUT FLOAT32 (the reference
// returns jax f32; the comparator's "(bf16)" label is the bf16-quantized-ref
// tolerance mode, not the buffer dtype). R2-R4 failed only because they wrote
// N bf16 ushorts into an N-float buffer (second half stayed zero -> absmax
// exactly max|bf16(ref)| = 0.73046875). R1's NaN = f32 x misread as bf16.
// This round: identical structure to R4, store float.

#define NPATCH 196
#define IMG    784

__global__ __launch_bounds__(256) void fraud_kernel(
    const float* __restrict__ x,      // [B, 784] f32
    const float* __restrict__ cp,     // [785]    f32
    float* __restrict__ out,          // [B] f32
    int B)
{
    const int wave = threadIdx.x >> 6;
    const int lane = threadIdx.x & 63;
    const int waveStride = gridDim.x * 4;

    for (int b = blockIdx.x * 4 + wave; b < B; b += waveStride) {
        const float* xb = x + (size_t)b * IMG;

        float acc = 0.f;
        #pragma unroll
        for (int it = 0; it < 4; ++it) {
            const int p = it * 64 + lane;          // patch index
            if (p < NPATCH) {
                const int gi = p / 14;
                const int gj = p - gi * 14;
                const int base = gi * 56 + gj * 2;
                const float c0 = __cosf(xb[base]);
                const float c1 = __cosf(xb[base + 1]);
                const float c2 = __cosf(xb[base + 28]);
                const float c3 = __cosf(xb[base + 29]);
                const float w0 = cp[4 * p + 0];
                const float w1 = cp[4 * p + 1];
                const float w2 = cp[4 * p + 2];
                const float w3 = cp[4 * p + 3];
                acc += c0 * fmaf(c1, fmaf(c2, fmaf(c3, w3, w2), w1), w0);
            }
        }

        // wave64 reduction to lane 0
        #pragma unroll
        for (int off = 32; off > 0; off >>= 1)
            acc += __shfl_down(acc, off, 64);

        if (lane == 0) {
            const float c = cosf(acc);             // |acc| ~ up to ±60: full range reduction
            out[b] = 1.f / (1.f + __expf(-c));     // sigmoid, stored as f32
        }
    }
}

extern "C" void kernel_launch(void* const* d_in, const int* in_sizes, int n_in,
                              void* d_out, int out_size, void* d_ws, size_t ws_size,
                              hipStream_t stream) {
    const float* x  = (const float*)d_in[0];   // [B,1,28,28] f32
    // d_in[1] = patch_params: provably unused (RZ phases cancel in |amp|^2)
    const float* cp = (const float*)d_in[2];   // [785] f32
    float* out = (float*)d_out;                // f32 [B]

    const int B = out_size;                    // elements == batch (4096)
    int blocks = (B + 3) / 4;                  // 4 waves per 256-thread block
    if (blocks > 4096) blocks = 4096;
    if (blocks < 1) blocks = 1;
    fraud_kernel<<<blocks, 256, 0, stream>>>(x, cp, out, B);
}